// Round 8
// baseline (664.473 us; speedup 1.0000x reference)
//
#include <hip/hip_runtime.h>

// ElmanRNN via MFMA, v4: BATCH=4096, SEQ=512, IN=2, HID=128, OUT=1
// h_{t+1} = tanh(h_t @ Wh^T + x_t @ Wx^T + b);  out = h_S @ Who^T + b_ho
//
// R4/R5/R6 invariant: ~2200 cy/step/CU regardless of wave count and LDS
// traffic (halving A-reads + conflicts in R6 changed nothing). Static
// critical path of one step is only ~500-600 cy -> the gap is EXPOSED SERIAL
// LATENCY of a single barrier-coupled recurrence per CU.
//
// v4: BM=8, grid=512 -> TWO independent recurrences per CU. Different blocks
// have independent barriers, so the HW scheduler interleaves their critical
// paths (latency hiding with zero code complexity). MFMA tile stays 16 rows
// (rows 8-15 compute a bounded garbage recurrence: tanh keeps them in
// [-1,1], MFMA rows don't mix, x-term reads row rr&7 to stay in bounds —
// provably cannot contaminate valid rows 0-7).
//
// Unchanged from R6: interleaved (hhi,hlo) ext-K=256 h plane, duplicated-pair
// B fragments (2 passes = compensated (Whi+Wlo)*(hhi+hlo)), XOR swizzle
// byte ^= (row&7)<<4, hoisted LDS offsets, cvt_pk write path.

constexpr int BATCH   = 4096;
constexpr int SEQ     = 512;
constexpr int INP     = 2;
constexpr int HID     = 128;
constexpr int BM      = 8;     // batch rows per block (rows 8-15 of tile: garbage)
constexpr int TROWS   = 16;    // MFMA tile rows
constexpr int THREADS = 256;   // 4 waves; 2 blocks/CU -> 2 waves/SIMD
constexpr int XCHUNK  = 128;   // time steps of x staged per chunk
constexpr int XROW    = XCHUNK * INP + 4;   // 260 floats: pad for bank spread

typedef short bf16x8 __attribute__((ext_vector_type(8)));
typedef float f32x4  __attribute__((ext_vector_type(4)));
typedef unsigned int u32x4 __attribute__((ext_vector_type(4)));

__device__ inline unsigned cvt_pk_bf16(float a, float b) {
    unsigned r;
    asm("v_cvt_pk_bf16_f32 %0, %1, %2" : "=v"(r) : "v"(a), "v"(b));
    return r;
}

__global__ __launch_bounds__(THREADS, 2)
void elman_mfma4(const float* __restrict__ x,
                 const float* __restrict__ W_ih,
                 const float* __restrict__ b_ih,
                 const float* __restrict__ W_ho,
                 const float* __restrict__ b_ho,
                 float* __restrict__ out)
{
    // interleaved (hhi,hlo) plane: [buf][row 16][ext 256] bf16, 512 B/row
    __shared__ unsigned short hlds[2][TROWS][2 * HID];   // 16 KB
    __shared__ float xs[BM][XROW];                       // 8.3 KB
    __shared__ float red[BM][8];

    const int tid  = threadIdx.x;
    const int lane = tid & 63;
    const int w    = tid >> 6;        // wave id 0..3 -> j range [32w, 32w+32)
    const int l15  = lane & 15;
    const int g    = lane >> 4;       // 0..3
    const int B0   = blockIdx.x * BM;

    // ---- stationary B fragments for both col-tiles (duplicated-pair) ----
    int jc[2];
    jc[0] = w * 32 + l15;
    jc[1] = w * 32 + 16 + l15;
    bf16x8 Bhi[2][8], Blo[2][8];
    float wx0[2], wx1[2], bj[2], who[2];
    #pragma unroll
    for (int c = 0; c < 2; ++c) {
        const float* Wrow = W_ih + (size_t)jc[c] * (INP + HID);
        wx0[c] = Wrow[0];
        wx1[c] = Wrow[1];
        bj[c]  = b_ih[jc[c]];
        who[c] = W_ho[jc[c]];
        #pragma unroll
        for (int kt = 0; kt < 8; ++kt) {
            const float4 wv = *reinterpret_cast<const float4*>(Wrow + INP + kt * 16 + g * 4);
            const float wm[4] = {wv.x, wv.y, wv.z, wv.w};
            u32x4 hi, lo;
            #pragma unroll
            for (int m = 0; m < 4; ++m) {
                const unsigned c1 = cvt_pk_bf16(wm[m], wm[m]);   // (bf(w), bf(w))
                const float whf = __uint_as_float(c1 << 16);
                const float wl  = wm[m] - whf;
                hi[m] = c1;
                lo[m] = cvt_pk_bf16(wl, wl);
            }
            Bhi[c][kt] = __builtin_bit_cast(bf16x8, hi);
            Blo[c][kt] = __builtin_bit_cast(bf16x8, lo);
        }
    }

    // ---- hoisted swizzled LDS offsets ----
    int roff[8];
    #pragma unroll
    for (int kt = 0; kt < 8; ++kt)
        roff[kt] = l15 * 512 + ((kt * 64 + g * 16) ^ ((l15 & 7) << 4));
    int woff[2][4];
    #pragma unroll
    for (int c = 0; c < 2; ++c)
        #pragma unroll
        for (int i = 0; i < 4; ++i) {
            const int rr = g * 4 + i;
            woff[c][i] = rr * 512 + ((4 * jc[c]) ^ ((rr & 7) << 4));
        }

    // ---- h0 = 0 (16 KB = 1024 float4, 256 threads x 4) ----
    #pragma unroll
    for (int q = 0; q < 4; ++q)
        reinterpret_cast<float4*>(hlds)[tid + 256 * q] = float4{0.f, 0.f, 0.f, 0.f};

    // ---- stage x chunk 0 (8 rows x 256 floats; 2 float4 per thread) ----
    const int sr = tid >> 5;            // 0..7
    const int sc = (tid & 31) * 4;      // 0..124
    {
        const float* s0 = x + (size_t)(B0 + sr) * (SEQ * INP) + sc;
        *reinterpret_cast<float4*>(&xs[sr][sc])       = *reinterpret_cast<const float4*>(s0);
        *reinterpret_cast<float4*>(&xs[sr][sc + 128]) = *reinterpret_cast<const float4*>(s0 + 128);
    }
    __syncthreads();

    const char* hb0 = (const char*)&hlds[0][0][0];
    const char* hb1 = (const char*)&hlds[1][0][0];
    int p = 0;
    float hv[2][4];                     // final-step h (epilogue; g<2 valid)
    #pragma unroll
    for (int c = 0; c < 2; ++c)
        #pragma unroll
        for (int i = 0; i < 4; ++i) hv[c][i] = 0.f;

    #pragma unroll 1
    for (int t = 0; t < SEQ; ++t) {
        const int tt = t & (XCHUNK - 1);
        if (t && tt == 0) {
            const size_t cb = (size_t)(t >> 7) * (XCHUNK * INP);
            const float* s0 = x + (size_t)(B0 + sr) * (SEQ * INP) + cb + sc;
            *reinterpret_cast<float4*>(&xs[sr][sc])       = *reinterpret_cast<const float4*>(s0);
            *reinterpret_cast<float4*>(&xs[sr][sc + 128]) = *reinterpret_cast<const float4*>(s0 + 128);
            __syncthreads();
        }

        // ---- A fragments: full interleaved h row-slice (8 x b128) ----
        const char* hp = p ? hb1 : hb0;
        bf16x8 A[8];
        #pragma unroll
        for (int kt = 0; kt < 8; ++kt)
            A[kt] = *reinterpret_cast<const bf16x8*>(hp + roff[kt]);

        // ---- 4 independent MFMA chains over ext-K=256 ----
        f32x4 a00 = {0.f, 0.f, 0.f, 0.f};   // tile 0, Bhi
        f32x4 a10 = {0.f, 0.f, 0.f, 0.f};   // tile 0, Blo
        f32x4 a01 = {0.f, 0.f, 0.f, 0.f};   // tile 1, Bhi
        f32x4 a11 = {0.f, 0.f, 0.f, 0.f};   // tile 1, Blo
        #pragma unroll
        for (int kt = 0; kt < 8; ++kt) {
            a00 = __builtin_amdgcn_mfma_f32_16x16x32_bf16(A[kt], Bhi[0][kt], a00, 0, 0, 0);
            a10 = __builtin_amdgcn_mfma_f32_16x16x32_bf16(A[kt], Blo[0][kt], a10, 0, 0, 0);
            a01 = __builtin_amdgcn_mfma_f32_16x16x32_bf16(A[kt], Bhi[1][kt], a01, 0, 0, 0);
            a11 = __builtin_amdgcn_mfma_f32_16x16x32_bf16(A[kt], Blo[1][kt], a11, 0, 0, 0);
        }

        // ---- x-term (row rr&7 keeps garbage rows in-bounds) ----
        float2 xv[4];
        #pragma unroll
        for (int i = 0; i < 4; ++i)
            xv[i] = *reinterpret_cast<const float2*>(&xs[(g * 4 + i) & 7][2 * tt]);

        // ---- bias + tanh + cvt_pk split + 4B packed store (8 outputs) ----
        char* wp = (char*)(p ? hb0 : hb1);
        #pragma unroll
        for (int c = 0; c < 2; ++c) {
            const f32x4 ah = c ? a01 : a00;
            const f32x4 al = c ? a11 : a10;
            #pragma unroll
            for (int i = 0; i < 4; ++i) {
                const float acc = (ah[i] + al[i])
                                + fmaf(wx0[c], xv[i].x, fmaf(wx1[c], xv[i].y, bj[c]));
                const float e = __expf(acc + acc);
                const float h = 1.0f - __fdividef(2.0f, e + 1.0f);   // tanh
                hv[c][i] = h;
                const unsigned c1  = cvt_pk_bf16(h, h);
                const float    hbf = __uint_as_float(c1 << 16);
                const float    lo  = h - hbf;
                const unsigned c2  = cvt_pk_bf16(h, lo);             // (bf(h), bf(lo))
                *reinterpret_cast<unsigned*>(wp + woff[c][i]) = c2;
            }
        }
        __syncthreads();
        p ^= 1;
    }

    // ---- epilogue: out[r] = sum_j Who[j]*h[r][j] + b_ho  (rows 0-7) ----
    #pragma unroll
    for (int c = 0; c < 2; ++c) {
        #pragma unroll
        for (int i = 0; i < 4; ++i) {
            float v = who[c] * hv[c][i];
            v += __shfl_xor(v, 1);
            v += __shfl_xor(v, 2);
            v += __shfl_xor(v, 4);
            v += __shfl_xor(v, 8);     // reduce over the 16 cols of the tile
            if (l15 == 0 && g < 2) red[g * 4 + i][2 * w + c] = v;
        }
    }
    __syncthreads();
    if (tid < BM) {
        float s = b_ho[0];
        #pragma unroll
        for (int q = 0; q < 8; ++q) s += red[tid][q];
        out[B0 + tid] = s;
    }
}

extern "C" void kernel_launch(void* const* d_in, const int* in_sizes, int n_in,
                              void* d_out, int out_size, void* d_ws, size_t ws_size,
                              hipStream_t stream)
{
    (void)in_sizes; (void)n_in; (void)out_size; (void)d_ws; (void)ws_size;
    const float* x    = (const float*)d_in[0];
    const float* W_ih = (const float*)d_in[1];
    const float* b_ih = (const float*)d_in[2];
    const float* W_ho = (const float*)d_in[3];
    const float* b_ho = (const float*)d_in[4];
    float* out = (float*)d_out;

    dim3 grid(BATCH / BM);     // 512 blocks = 2 per CU
    dim3 block(THREADS);
    elman_mfma4<<<grid, block, 0, stream>>>(x, W_ih, b_ih, W_ho, b_ho, out);
}

// Round 10
// 410.997 us; speedup vs baseline: 1.6167x; 1.6167x over previous
//
#include <hip/hip_runtime.h>

// ElmanRNN via MFMA, v5b: BATCH=4096, SEQ=512, IN=2, HID=128, OUT=1
// h_{t+1} = tanh(h_t @ Wh^T + x_t @ Wx^T + b);  out = h_S @ Who^T + b_ho
//
// Constraint web (R4-R7): 4096 rows / 256 CUs = 16 rows/CU fixed; BM<16
// wastes MFMA rows (R7: 2x work -> 1.65x time, throughput-busy), BM>16
// under-fills the grid. R4 (12 MFMA, 4-deep chains) remains fastest; R5/R6
// (16 MFMA, 8-deep) are ~50us slower => MFMA dep-chain latency is a real
// serial component (~30cy/link).
//
// v5 = R4 structure (512 thr, 8 waves=2/SIMD, BM=16 all valid, 3-product
// separate hi/lo planes: Whi*hhi + Wlo*hhi + Whi*hlo) with:
//   1. chain depth 4 -> 2: six accumulators (a0a..a2b), 12 MFMA.
//   2. cvt_pk write path (R5-proven): ~5 VALU/output vs R4's ~10 bit-ops.
//   3. light barrier (lgkmcnt-only drain + s_barrier) instead of
//      __syncthreads' full vmcnt+lgkmcnt drain.
// v5b: fix R8 compile error — no LDS-pointer array initializer (gfx950
// rejects addrspacecast in static init); use scalar ptrs + ternary select.

constexpr int BATCH   = 4096;
constexpr int SEQ     = 512;
constexpr int INP     = 2;
constexpr int HID     = 128;
constexpr int BM      = 16;    // batch rows per block (all valid)
constexpr int THREADS = 512;   // 8 waves, 1 block/CU, 2 waves/SIMD
constexpr int XCHUNK  = 128;   // time steps of x staged per chunk
constexpr int XROW    = XCHUNK * INP + 4;   // 260 floats: bank-spread pad

typedef short bf16x8 __attribute__((ext_vector_type(8)));
typedef float f32x4  __attribute__((ext_vector_type(4)));

__device__ inline unsigned cvt_pk_bf16(float a, float b) {
    unsigned r;
    asm("v_cvt_pk_bf16_f32 %0, %1, %2" : "=v"(r) : "v"(a), "v"(b));
    return r;
}
__device__ inline unsigned short f2bf(float f) {          // RNE, prologue only
    unsigned u = __float_as_uint(f);
    return (unsigned short)((u + 0x7FFFu + ((u >> 16) & 1u)) >> 16);
}
__device__ inline float bf2f(unsigned short s) {
    return __uint_as_float(((unsigned)s) << 16);
}
// LDS-only barrier: drain own LDS ops, rendezvous. (No vmcnt drain; every
// ds_write of staged data already data-depends on its global load.)
__device__ inline void lds_barrier() {
    asm volatile("s_waitcnt lgkmcnt(0)\n\ts_barrier" ::: "memory");
}

__global__ __launch_bounds__(THREADS, 1)
void elman_mfma5(const float* __restrict__ x,
                 const float* __restrict__ W_ih,
                 const float* __restrict__ b_ih,
                 const float* __restrict__ W_ho,
                 const float* __restrict__ b_ho,
                 float* __restrict__ out)
{
    __shared__ unsigned short hlds[2][2][BM][HID];  // [buf][hi/lo][r][j] 16 KB
    __shared__ float xs[BM][XROW];                  // 16.6 KB staged x chunk
    __shared__ float red[BM][8];                    // epilogue partials

    const int tid  = threadIdx.x;
    const int lane = tid & 63;
    const int w    = tid >> 6;        // wave id 0..7 -> j-tile [16w, 16w+16)
    const int l15  = lane & 15;
    const int g    = lane >> 4;       // 0..3
    const int j    = w * 16 + l15;    // output column this lane owns
    const int B0   = blockIdx.x * BM;

    // ---- stationary B fragments, hi/lo split (slot map k = kt*32+g*8+i) ----
    bf16x8 bhi[4], blo[4];
    {
        const float* Wrow = W_ih + (size_t)j * (INP + HID) + INP;
        #pragma unroll
        for (int kt = 0; kt < 4; ++kt) {
            const int k0 = kt * 32 + g * 8;
            #pragma unroll
            for (int i = 0; i < 8; ++i) {
                const float wv = Wrow[k0 + i];
                const unsigned short hi = f2bf(wv);
                bhi[kt][i] = (short)hi;
                blo[kt][i] = (short)f2bf(wv - bf2f(hi));
            }
        }
    }
    const float* Wrow0 = W_ih + (size_t)j * (INP + HID);
    const float wx0 = Wrow0[0];
    const float wx1 = Wrow0[1];
    const float bj  = b_ih[j];

    // ---- hoisted swizzled LDS offsets (byte ^= (row&7)<<4) ----
    int roff[4];
    #pragma unroll
    for (int kt = 0; kt < 4; ++kt)
        roff[kt] = l15 * 256 + ((kt * 64 + g * 16) ^ ((l15 & 7) << 4));
    int woff[4];
    #pragma unroll
    for (int i = 0; i < 4; ++i) {
        const int rr = g * 4 + i;
        woff[i] = rr * 256 + ((2 * j) ^ ((rr & 7) << 4));
    }

    // ---- h0 = 0 (16 KB = 1024 float4; 512 threads x 2) ----
    reinterpret_cast<float4*>(hlds)[tid]       = float4{0.f, 0.f, 0.f, 0.f};
    reinterpret_cast<float4*>(hlds)[tid + 512] = float4{0.f, 0.f, 0.f, 0.f};

    // ---- stage x chunk 0 (16 rows x 256 floats; 2 float4/thread) ----
    const int sr = tid >> 5;            // 0..15
    const int so = (tid & 31) * 8;      // 0..248
    {
        const float* src = x + (size_t)(B0 + sr) * (SEQ * INP) + so;
        *reinterpret_cast<float4*>(&xs[sr][so])     = *reinterpret_cast<const float4*>(src);
        *reinterpret_cast<float4*>(&xs[sr][so + 4]) = *reinterpret_cast<const float4*>(src + 4);
    }
    lds_barrier();

    const char* hbuf0 = (const char*)&hlds[0][0][0][0];
    const char* hbuf1 = (const char*)&hlds[1][0][0][0];
    int p = 0;
    float hv[4] = {0.f, 0.f, 0.f, 0.f};

    #pragma unroll 1
    for (int t = 0; t < SEQ; ++t) {
        const int tt = t & (XCHUNK - 1);
        if (t && tt == 0) {
            // prev end-of-step barrier guarantees xs no longer read
            const float* src = x + (size_t)(B0 + sr) * (SEQ * INP)
                                 + (size_t)(t >> 7) * (XCHUNK * INP) + so;
            *reinterpret_cast<float4*>(&xs[sr][so])     = *reinterpret_cast<const float4*>(src);
            *reinterpret_cast<float4*>(&xs[sr][so + 4]) = *reinterpret_cast<const float4*>(src + 4);
            lds_barrier();
        }

        // ---- A fragments from buf p (4 hi + 4 lo b128 reads) ----
        const char* hp = p ? hbuf1 : hbuf0;
        bf16x8 ahi[4], alo[4];
        #pragma unroll
        for (int kt = 0; kt < 4; ++kt) {
            ahi[kt] = *reinterpret_cast<const bf16x8*>(hp + roff[kt]);
            alo[kt] = *reinterpret_cast<const bf16x8*>(hp + 4096 + roff[kt]);
        }

        // ---- 3-product GEMM, 6 chains of depth 2 (12 MFMA) ----
        f32x4 a0a = {0.f,0.f,0.f,0.f}, a0b = {0.f,0.f,0.f,0.f};
        f32x4 a1a = {0.f,0.f,0.f,0.f}, a1b = {0.f,0.f,0.f,0.f};
        f32x4 a2a = {0.f,0.f,0.f,0.f}, a2b = {0.f,0.f,0.f,0.f};
        a0a = __builtin_amdgcn_mfma_f32_16x16x32_bf16(ahi[0], bhi[0], a0a, 0, 0, 0);
        a1a = __builtin_amdgcn_mfma_f32_16x16x32_bf16(alo[0], bhi[0], a1a, 0, 0, 0);
        a2a = __builtin_amdgcn_mfma_f32_16x16x32_bf16(ahi[0], blo[0], a2a, 0, 0, 0);
        a0b = __builtin_amdgcn_mfma_f32_16x16x32_bf16(ahi[1], bhi[1], a0b, 0, 0, 0);
        a1b = __builtin_amdgcn_mfma_f32_16x16x32_bf16(alo[1], bhi[1], a1b, 0, 0, 0);
        a2b = __builtin_amdgcn_mfma_f32_16x16x32_bf16(ahi[1], blo[1], a2b, 0, 0, 0);
        a0a = __builtin_amdgcn_mfma_f32_16x16x32_bf16(ahi[2], bhi[2], a0a, 0, 0, 0);
        a1a = __builtin_amdgcn_mfma_f32_16x16x32_bf16(alo[2], bhi[2], a1a, 0, 0, 0);
        a2a = __builtin_amdgcn_mfma_f32_16x16x32_bf16(ahi[2], blo[2], a2a, 0, 0, 0);
        a0b = __builtin_amdgcn_mfma_f32_16x16x32_bf16(ahi[3], bhi[3], a0b, 0, 0, 0);
        a1b = __builtin_amdgcn_mfma_f32_16x16x32_bf16(alo[3], bhi[3], a1b, 0, 0, 0);
        a2b = __builtin_amdgcn_mfma_f32_16x16x32_bf16(ahi[3], blo[3], a2b, 0, 0, 0);

        // ---- x-term + bias + tanh + cvt_pk split + 2x b16 store ----
        char* hn = (char*)(p ? hbuf0 : hbuf1);  // next buf (hi plane base)
        #pragma unroll
        for (int i = 0; i < 4; ++i) {
            const int rr = g * 4 + i;           // D-row (batch row)
            const float2 xv = *reinterpret_cast<const float2*>(&xs[rr][2 * tt]);
            const float acc = ((a0a[i] + a0b[i]) + (a1a[i] + a1b[i]))
                            + (a2a[i] + a2b[i])
                            + fmaf(wx0, xv.x, fmaf(wx1, xv.y, bj));
            const float e = __expf(acc + acc);
            const float h = 1.0f - __fdividef(2.0f, e + 1.0f);   // tanh(acc)
            hv[i] = h;
            const unsigned c1  = cvt_pk_bf16(h, h);          // low16 = bf(h)
            const float    hbf = __uint_as_float(c1 << 16);
            const unsigned c2  = cvt_pk_bf16(h - hbf, h - hbf);  // low16 = bf(lo)
            *reinterpret_cast<unsigned short*>(hn + woff[i])        = (unsigned short)c1;
            *reinterpret_cast<unsigned short*>(hn + 4096 + woff[i]) = (unsigned short)c2;
        }
        lds_barrier();
        p ^= 1;
    }

    // ---- epilogue: out[r] = sum_j Who[j]*h[r][j] + b_ho ----
    const float who = W_ho[j];
    #pragma unroll
    for (int i = 0; i < 4; ++i) {
        float v = who * hv[i];
        v += __shfl_xor(v, 1);
        v += __shfl_xor(v, 2);
        v += __shfl_xor(v, 4);
        v += __shfl_xor(v, 8);     // reduce over the 16 cols of this tile
        if (l15 == 0) red[g * 4 + i][w] = v;
    }
    __syncthreads();
    if (tid < BM) {
        float s = b_ho[0];
        #pragma unroll
        for (int q = 0; q < 8; ++q) s += red[tid][q];
        out[B0 + tid] = s;
    }
}

extern "C" void kernel_launch(void* const* d_in, const int* in_sizes, int n_in,
                              void* d_out, int out_size, void* d_ws, size_t ws_size,
                              hipStream_t stream)
{
    (void)in_sizes; (void)n_in; (void)out_size; (void)d_ws; (void)ws_size;
    const float* x    = (const float*)d_in[0];
    const float* W_ih = (const float*)d_in[1];
    const float* b_ih = (const float*)d_in[2];
    const float* W_ho = (const float*)d_in[3];
    const float* b_ho = (const float*)d_in[4];
    float* out = (float*)d_out;

    dim3 grid(BATCH / BM);     // 256 blocks = 1 per CU
    dim3 block(THREADS);
    elman_mfma5<<<grid, block, 0, stream>>>(x, W_ih, b_ih, W_ho, b_ho, out);
}

// Round 11
// 353.784 us; speedup vs baseline: 1.8782x; 1.1617x over previous
//
#include <hip/hip_runtime.h>

// ElmanRNN via MFMA, v6 = R4 (best measured: 374us) + full-width XOR swizzle.
// BATCH=4096, SEQ=512, IN=2, HID=128, OUT=1
// h_{t+1} = tanh(h_t @ Wh^T + x_t @ Wx^T + b);  out = h_S @ Who^T + b_ho
//
// R4-R9 ledger: ~2000-2200 cy/step/CU plateau across wave count / chain depth /
// write path / barrier type. Phase budget (m134: ds_read_b128 ~12cy/wave):
// A-reads = 64 wave-b128/CU-step ~770 cy = the largest phase, and
// SQ_LDS_BANK_CONFLICT tracks it exactly (R5/R9 8-wave: 3.37e7; R6 4-wave:
// 1.68e7 = exactly half). Old key (l15&7)<<4 made lanes l15 and l15+8 of each
// 16-lane issue group hit the SAME bank-set -> 2-way conflict every read.
//
// v6: widen key to 4 bits. Read row r with key r<<4; write row rr with key
// rr<<4. Row = 256 B so key occupies bits [7:4]; XOR with 16-aligned key
// permutes whole 16B blocks -> reader gets logical bytes in order; writer's
// 2B store (2j even, key 16-aligned) lands in the right block. Bijective per
// row; 16 lanes/group now cover all 32 banks exactly once -> conflict-free.
// ALL ELSE IDENTICAL TO R4.

constexpr int BATCH   = 4096;
constexpr int SEQ     = 512;
constexpr int INP     = 2;
constexpr int HID     = 128;
constexpr int BM      = 16;    // batch rows per block
constexpr int THREADS = 512;   // 8 waves
constexpr int XCHUNK  = 128;   // time steps of x staged per chunk

typedef short bf16x8 __attribute__((ext_vector_type(8)));
typedef float f32x4  __attribute__((ext_vector_type(4)));

__device__ inline unsigned short f2bf(float f) {          // round-to-nearest-even
    unsigned u = __float_as_uint(f);
    return (unsigned short)((u + 0x7FFFu + ((u >> 16) & 1u)) >> 16);
}
__device__ inline float bf2f(unsigned short s) {
    return __uint_as_float(((unsigned)s) << 16);
}

__global__ __launch_bounds__(THREADS, 2)
void elman_mfma6(const float* __restrict__ x,
                 const float* __restrict__ W_ih,
                 const float* __restrict__ b_ih,
                 const float* __restrict__ W_ho,
                 const float* __restrict__ b_ho,
                 float* __restrict__ out)
{
    __shared__ unsigned short hlds[2][2][BM][HID];  // [buf][hi/lo][r][j] = 16 KB
    __shared__ float xs[BM][XCHUNK][INP];           // 16 KB staged x chunk
    __shared__ float red[BM][8];                    // epilogue partials

    const int tid  = threadIdx.x;
    const int lane = tid & 63;
    const int w    = tid >> 6;        // wave id 0..7 -> j-tile [16w, 16w+16)
    const int l15  = lane & 15;
    const int g    = lane >> 4;       // 0..3
    const int j    = w * 16 + l15;    // output column this lane holds (D-layout)
    const int B0   = blockIdx.x * BM;

    // ---- stationary W fragments (B-operand), hi/lo bf16 split ----
    // B-frag slot (g,i) of k-tile kt <- W^T[k][j] = Wh[j][k], k = kt*32 + g*8 + i
    bf16x8 bhi[4], blo[4];
    {
        const float* Wrow = W_ih + (size_t)j * (INP + HID) + INP;
        #pragma unroll
        for (int kt = 0; kt < 4; ++kt) {
            const int k0 = kt * 32 + g * 8;
            #pragma unroll
            for (int i = 0; i < 8; ++i) {
                const float wv = Wrow[k0 + i];
                const unsigned short hi = f2bf(wv);
                const float lo = wv - bf2f(hi);
                bhi[kt][i] = (short)hi;
                blo[kt][i] = (short)f2bf(lo);
            }
        }
    }
    const float* Wrow0 = W_ih + (size_t)j * (INP + HID);
    const float wx0 = Wrow0[0];
    const float wx1 = Wrow0[1];
    const float bj  = b_ih[j];

    // ---- h0 = 0: zero buffer 0 (both planes, 8 KB) ----
    reinterpret_cast<float4*>(hlds)[tid] = float4{0.f, 0.f, 0.f, 0.f};

    // ---- stage x chunk 0 ----
    {
        const int row = tid >> 5;             // 0..15
        const int o8  = (tid & 31) * 8;       // float offset within row's 256
        const float* src = x + (size_t)(B0 + row) * (SEQ * INP) + o8;
        float* dst = &xs[row][0][0] + o8;
        *reinterpret_cast<float4*>(dst)     = *reinterpret_cast<const float4*>(src);
        *reinterpret_cast<float4*>(dst + 4) = *reinterpret_cast<const float4*>(src + 4);
    }
    __syncthreads();

    int p = 0;
    float hv[4] = {0.f, 0.f, 0.f, 0.f};   // final-step h values (epilogue)
    const int sw_r = l15 << 4;            // FULL 4-bit A-read swizzle key (r = l15)

    #pragma unroll 1
    for (int t = 0; t < SEQ; ++t) {
        const int tt = t & (XCHUNK - 1);
        if (t && tt == 0) {
            // previous end-of-step barrier guarantees xs no longer read
            const int row = tid >> 5;
            const int o8  = (tid & 31) * 8;
            const float* src = x + (size_t)(B0 + row) * (SEQ * INP)
                                 + (size_t)(t >> 7) * (XCHUNK * INP) + o8;
            float* dst = &xs[row][0][0] + o8;
            *reinterpret_cast<float4*>(dst)     = *reinterpret_cast<const float4*>(src);
            *reinterpret_cast<float4*>(dst + 4) = *reinterpret_cast<const float4*>(src + 4);
            __syncthreads();
        }

        // ---- read A fragments (h hi/lo) from buf p ----
        // A-frag slot (g,i) of k-tile kt <- h[r][k], r = l15, k = kt*32 + g*8 + i
        // (same k->slot map as B => contraction correct for any HW ordering)
        const char* hp = (const char*)&hlds[p][0][0][0];
        const char* lp = (const char*)&hlds[p][1][0][0];
        bf16x8 ahi[4], alo[4];
        #pragma unroll
        for (int kt = 0; kt < 4; ++kt) {
            const int off = l15 * 256 + ((kt * 64 + g * 16) ^ sw_r);
            ahi[kt] = *reinterpret_cast<const bf16x8*>(hp + off);
            alo[kt] = *reinterpret_cast<const bf16x8*>(lp + off);
        }

        // ---- 3-product split GEMM: Whi*hhi + Whi*hlo + Wlo*hhi ----
        f32x4 a0 = {0.f, 0.f, 0.f, 0.f};
        f32x4 a1 = {0.f, 0.f, 0.f, 0.f};
        f32x4 a2 = {0.f, 0.f, 0.f, 0.f};
        #pragma unroll
        for (int kt = 0; kt < 4; ++kt) {
            a0 = __builtin_amdgcn_mfma_f32_16x16x32_bf16(ahi[kt], bhi[kt], a0, 0, 0, 0);
            a1 = __builtin_amdgcn_mfma_f32_16x16x32_bf16(alo[kt], bhi[kt], a1, 0, 0, 0);
            a2 = __builtin_amdgcn_mfma_f32_16x16x32_bf16(ahi[kt], blo[kt], a2, 0, 0, 0);
        }

        // ---- x-term + bias + tanh + hi/lo split + write buf p^1 ----
        unsigned short* hn = &hlds[p ^ 1][0][0][0];
        unsigned short* ln = &hlds[p ^ 1][1][0][0];
        #pragma unroll
        for (int i = 0; i < 4; ++i) {
            const int rr = g * 4 + i;                      // D-row (batch row)
            const float2 xv = *reinterpret_cast<const float2*>(&xs[rr][tt][0]);
            const float acc = (a0[i] + a1[i] + a2[i])
                            + fmaf(wx0, xv.x, fmaf(wx1, xv.y, bj));
            const float e = __expf(2.0f * acc);
            const float h = 1.0f - __fdividef(2.0f, e + 1.0f);   // tanh(acc)
            hv[i] = h;
            const unsigned short hb = f2bf(h);
            const float lo = h - bf2f(hb);
            const int off = rr * 256 + ((2 * j) ^ (rr << 4));    // FULL 4-bit key
            *(unsigned short*)((char*)hn + off) = hb;
            *(unsigned short*)((char*)ln + off) = f2bf(lo);
        }
        __syncthreads();
        p ^= 1;
    }

    // ---- epilogue: out[r] = sum_j Who[j]*h[r][j] + b_ho ----
    const float who = W_ho[j];
    float pr[4];
    #pragma unroll
    for (int i = 0; i < 4; ++i) {
        float v = who * hv[i];
        v += __shfl_xor(v, 1);
        v += __shfl_xor(v, 2);
        v += __shfl_xor(v, 4);
        v += __shfl_xor(v, 8);     // 16-lane j-reduction within wave's tile
        pr[i] = v;
    }
    if (l15 == 0) {
        #pragma unroll
        for (int i = 0; i < 4; ++i) red[g * 4 + i][w] = pr[i];
    }
    __syncthreads();
    if (tid < BM) {
        float s = b_ho[0];
        #pragma unroll
        for (int q = 0; q < 8; ++q) s += red[tid][q];
        out[B0 + tid] = s;
    }
}

extern "C" void kernel_launch(void* const* d_in, const int* in_sizes, int n_in,
                              void* d_out, int out_size, void* d_ws, size_t ws_size,
                              hipStream_t stream)
{
    (void)in_sizes; (void)n_in; (void)out_size; (void)d_ws; (void)ws_size;
    const float* x    = (const float*)d_in[0];
    const float* W_ih = (const float*)d_in[1];
    const float* b_ih = (const float*)d_in[2];
    const float* W_ho = (const float*)d_in[3];
    const float* b_ho = (const float*)d_in[4];
    float* out = (float*)d_out;

    dim3 grid(BATCH / BM);     // 256 blocks = 1 per CU
    dim3 block(THREADS);
    elman_mfma6<<<grid, block, 0, stream>>>(x, W_ih, b_ih, W_ho, b_ho, out);
}

// Round 12
// 329.024 us; speedup vs baseline: 2.0195x; 1.0753x over previous
//
#include <hip/hip_runtime.h>

// ElmanRNN via MFMA, v7 = R11 + OPERAND SWAP (compute W·h^T, not h·W^T).
// BATCH=4096, SEQ=512, IN=2, HID=128, OUT=1
//
// R11 ledger: conflicts 3.37e7 -> 1.5e5 via full 4-bit XOR key; 354us bench.
// Remaining budget (1925 cy/step/CU): LDS pipe is the dominant resource:
// 64 b128 h-reads (~770cy) + 32 b64 x-reads (~250) + 64 b16 h-writes (~250).
//
// v7: pass W frags as the MFMA A-operand and h frags as B. h-reads stay
// byte-identical (lane l15 reads row l15). D-layout flips: lane now holds
// batch row r=l15 x 4 consecutive j columns ->
//   - h-write: one ds_write_b64 per plane (16 wave-writes/step vs 64)
//   - x-term: x[r=l15] only -> 1 ds_read_b64/wave/step (vs 4), from a
//     TRANSPOSED xs[t][b] staging buffer (conflict-free: 16 lanes x 8B
//     = 128B contiguous).
// LDS instr/step: 160 -> 88. Swap correctness is implied by R4's numerical
// pass (equal A/B k-slot maps + row/col = lane&15). Swizzle: key (r<<4)
// XORs only byte bits 4-7, 8B writes sit within one 16B block -> reader
// (b128 at 16B-aligned ^ key) and writer agree; write banks spread by key,
// residual 2-way is free (m136).

constexpr int BATCH   = 4096;
constexpr int SEQ     = 512;
constexpr int INP     = 2;
constexpr int HID     = 128;
constexpr int BM      = 16;    // batch rows per block
constexpr int THREADS = 512;   // 8 waves, 1 block/CU, 2 waves/SIMD
constexpr int XCHUNK  = 128;   // time steps of x staged per chunk

typedef short bf16x8 __attribute__((ext_vector_type(8)));
typedef float f32x4  __attribute__((ext_vector_type(4)));

__device__ inline unsigned short f2bf(float f) {          // round-to-nearest-even
    unsigned u = __float_as_uint(f);
    return (unsigned short)((u + 0x7FFFu + ((u >> 16) & 1u)) >> 16);
}
__device__ inline float bf2f(unsigned short s) {
    return __uint_as_float(((unsigned)s) << 16);
}
__device__ inline unsigned cvt_pk_bf16(float a, float b) { // lo=bf(a), hi=bf(b)
    unsigned r;
    asm("v_cvt_pk_bf16_f32 %0, %1, %2" : "=v"(r) : "v"(a), "v"(b));
    return r;
}

__global__ __launch_bounds__(THREADS, 2)
void elman_mfma7(const float* __restrict__ x,
                 const float* __restrict__ W_ih,
                 const float* __restrict__ b_ih,
                 const float* __restrict__ W_ho,
                 const float* __restrict__ b_ho,
                 float* __restrict__ out)
{
    __shared__ unsigned short hlds[2][2][BM][HID];  // [buf][hi/lo][r][j] = 16 KB
    __shared__ float2 xs[XCHUNK][BM];               // 16 KB, TRANSPOSED [t][b]
    __shared__ float red[BM][8];                    // epilogue partials

    const int tid  = threadIdx.x;
    const int lane = tid & 63;
    const int w    = tid >> 6;        // wave id 0..7 -> j-tile [16w, 16w+16)
    const int l15  = lane & 15;
    const int g    = lane >> 4;       // 0..3
    const int B0   = blockIdx.x * BM;

    // ---- stationary W fragments (now the A-operand), hi/lo bf16 split ----
    // A-frag slot (g,i) of k-tile kt <- W[j = w*16 + l15][k = kt*32 + g*8 + i]
    bf16x8 whi[4], wlo[4];
    {
        const float* Wrow = W_ih + (size_t)(w * 16 + l15) * (INP + HID) + INP;
        #pragma unroll
        for (int kt = 0; kt < 4; ++kt) {
            const int k0 = kt * 32 + g * 8;
            #pragma unroll
            for (int i = 0; i < 8; ++i) {
                const float wv = Wrow[k0 + i];
                const unsigned short hi = f2bf(wv);
                whi[kt][i] = (short)hi;
                wlo[kt][i] = (short)f2bf(wv - bf2f(hi));
            }
        }
    }

    // ---- per-reg coefficients for the 4 j's this lane RECEIVES in D ----
    // D: col = lane&15 = r (batch row), row = g*4 + reg -> j = w*16 + g*4 + reg
    float wx0v[4], wx1v[4], bjv[4], whov[4];
    #pragma unroll
    for (int reg = 0; reg < 4; ++reg) {
        const int jj = w * 16 + g * 4 + reg;
        const float* Wr = W_ih + (size_t)jj * (INP + HID);
        wx0v[reg] = Wr[0];
        wx1v[reg] = Wr[1];
        bjv[reg]  = b_ih[jj];
        whov[reg] = W_ho[jj];
    }

    // ---- hoisted swizzled LDS offsets (key = r<<4, full 4 bits) ----
    int roff[4];
    #pragma unroll
    for (int kt = 0; kt < 4; ++kt)
        roff[kt] = l15 * 256 + ((kt * 64 + g * 16) ^ (l15 << 4));
    // write: row r=l15, logical in-row byte 2*j0 = w*32 + g*8
    const int woff = l15 * 256 + (((w * 32 + (g & 2) * 8)) ^ (l15 << 4)) + (g & 1) * 8;

    // ---- h0 = 0 (16 KB = 1024 float4; 512 threads x 2) ----
    reinterpret_cast<float4*>(hlds)[tid]       = float4{0.f, 0.f, 0.f, 0.f};
    reinterpret_cast<float4*>(hlds)[tid + 512] = float4{0.f, 0.f, 0.f, 0.f};

    // ---- stage x chunk 0, transposed: xs[t][b] ----
    const int sr = tid >> 5;            // 0..15 (batch row)
    const int so = (tid & 31) * 8;      // float offset within row's 256
    {
        const float* src = x + (size_t)(B0 + sr) * (SEQ * INP) + so;
        const float4 v0 = *reinterpret_cast<const float4*>(src);
        const float4 v1 = *reinterpret_cast<const float4*>(src + 4);
        const int t0 = so >> 1;         // timestep of v0.xy
        xs[t0 + 0][sr] = float2{v0.x, v0.y};
        xs[t0 + 1][sr] = float2{v0.z, v0.w};
        xs[t0 + 2][sr] = float2{v1.x, v1.y};
        xs[t0 + 3][sr] = float2{v1.z, v1.w};
    }
    __syncthreads();

    int p = 0;
    float hv[4] = {0.f, 0.f, 0.f, 0.f};   // final-step h (row l15, 4 j's)

    #pragma unroll 1
    for (int t = 0; t < SEQ; ++t) {
        const int tt = t & (XCHUNK - 1);
        if (t && tt == 0) {
            // previous end-of-step barrier guarantees xs no longer read
            const float* src = x + (size_t)(B0 + sr) * (SEQ * INP)
                                 + (size_t)(t >> 7) * (XCHUNK * INP) + so;
            const float4 v0 = *reinterpret_cast<const float4*>(src);
            const float4 v1 = *reinterpret_cast<const float4*>(src + 4);
            const int t0 = so >> 1;
            xs[t0 + 0][sr] = float2{v0.x, v0.y};
            xs[t0 + 1][sr] = float2{v0.z, v0.w};
            xs[t0 + 2][sr] = float2{v1.x, v1.y};
            xs[t0 + 3][sr] = float2{v1.z, v1.w};
            __syncthreads();
        }

        // ---- read h fragments (B-operand) from buf p: row l15, hi+lo ----
        const char* hp = (const char*)&hlds[p][0][0][0];
        const char* lp = (const char*)&hlds[p][1][0][0];
        bf16x8 ahi[4], alo[4];
        #pragma unroll
        for (int kt = 0; kt < 4; ++kt) {
            ahi[kt] = *reinterpret_cast<const bf16x8*>(hp + roff[kt]);
            alo[kt] = *reinterpret_cast<const bf16x8*>(lp + roff[kt]);
        }

        // ---- 3-product split GEMM, SWAPPED: D = W · h^T ----
        // a0 = Whi·hhi, a1 = Whi·hlo, a2 = Wlo·hhi
        f32x4 a0 = {0.f, 0.f, 0.f, 0.f};
        f32x4 a1 = {0.f, 0.f, 0.f, 0.f};
        f32x4 a2 = {0.f, 0.f, 0.f, 0.f};
        #pragma unroll
        for (int kt = 0; kt < 4; ++kt) {
            a0 = __builtin_amdgcn_mfma_f32_16x16x32_bf16(whi[kt], ahi[kt], a0, 0, 0, 0);
            a1 = __builtin_amdgcn_mfma_f32_16x16x32_bf16(whi[kt], alo[kt], a1, 0, 0, 0);
            a2 = __builtin_amdgcn_mfma_f32_16x16x32_bf16(wlo[kt], ahi[kt], a2, 0, 0, 0);
        }

        // ---- x-term (single uniform-per-lane read) + tanh + pack + b64 writes
        const float2 xv = xs[tt][l15];
        float hcur[4];
        #pragma unroll
        for (int reg = 0; reg < 4; ++reg) {
            const float acc = (a0[reg] + a1[reg] + a2[reg])
                            + fmaf(wx0v[reg], xv.x, fmaf(wx1v[reg], xv.y, bjv[reg]));
            const float e = __expf(acc + acc);
            hcur[reg] = 1.0f - __fdividef(2.0f, e + 1.0f);   // tanh(acc)
            hv[reg] = hcur[reg];
        }
        // pack hi plane: (bf(h0),bf(h1)) , (bf(h2),bf(h3)); derive lo from packed
        const unsigned c01 = cvt_pk_bf16(hcur[0], hcur[1]);
        const unsigned c23 = cvt_pk_bf16(hcur[2], hcur[3]);
        const float h0b = __uint_as_float(c01 << 16);
        const float h1b = __uint_as_float(c01 & 0xFFFF0000u);
        const float h2b = __uint_as_float(c23 << 16);
        const float h3b = __uint_as_float(c23 & 0xFFFF0000u);
        const unsigned l01 = cvt_pk_bf16(hcur[0] - h0b, hcur[1] - h1b);
        const unsigned l23 = cvt_pk_bf16(hcur[2] - h2b, hcur[3] - h3b);

        char* hn = (char*)&hlds[p ^ 1][0][0][0];
        char* ln = (char*)&hlds[p ^ 1][1][0][0];
        *reinterpret_cast<uint2*>(hn + woff) = uint2{c01, c23};
        *reinterpret_cast<uint2*>(ln + woff) = uint2{l01, l23};

        __syncthreads();
        p ^= 1;
    }

    // ---- epilogue: out[r] = sum_j Who[j]*h[r][j] + b_ho ----
    // lane holds row r=l15, j = w*16+g*4+{0..3}
    float part = 0.f;
    #pragma unroll
    for (int reg = 0; reg < 4; ++reg) part = fmaf(whov[reg], hv[reg], part);
    part += __shfl_xor(part, 16);   // sum over g bit0
    part += __shfl_xor(part, 32);   // sum over g bit1
    if (lane < 16) red[l15][w] = part;
    __syncthreads();
    if (tid < BM) {
        float s = b_ho[0];
        #pragma unroll
        for (int q = 0; q < 8; ++q) s += red[tid][q];
        out[B0 + tid] = s;
    }
}

extern "C" void kernel_launch(void* const* d_in, const int* in_sizes, int n_in,
                              void* d_out, int out_size, void* d_ws, size_t ws_size,
                              hipStream_t stream)
{
    (void)in_sizes; (void)n_in; (void)out_size; (void)d_ws; (void)ws_size;
    const float* x    = (const float*)d_in[0];
    const float* W_ih = (const float*)d_in[1];
    const float* b_ih = (const float*)d_in[2];
    const float* W_ho = (const float*)d_in[3];
    const float* b_ho = (const float*)d_in[4];
    float* out = (float*)d_out;

    dim3 grid(BATCH / BM);     // 256 blocks = 1 per CU
    dim3 block(THREADS);
    elman_mfma7<<<grid, block, 0, stream>>>(x, W_ih, b_ih, W_ho, b_ho, out);
}

// Round 15
// 312.584 us; speedup vs baseline: 2.1257x; 1.0526x over previous
//
#include <hip/hip_runtime.h>

// ElmanRNN via MFMA, v10 = R11/v7 EXACT numerics + unroll-2 ping-pong only.
// BATCH=4096, SEQ=512, IN=2, HID=128, OUT=1
//
// R12/R13 lesson (decisive): W_h spectral radius ~0.99 -> edge-of-chaos
// recurrence, ~1e6 amplification of per-step perturbations over 512 steps.
// The v8 "accumulator preload" moved the x-term into the MFMA C-init — a
// ~1ulp/step re-association — which grew to the observed 6e-2 failure in
// BOTH v8 and v9. The R11 numeric path (2e-3, 9x margin) is load-bearing
// IN ITS EXACT FORM. Only bit-identical transforms allowed.
//
// v10 changes vs R11 (zero numeric delta by construction):
//   - unroll-2 ping-pong: explicit buf0->buf1 / buf1->buf0 step bodies with
//     fixed LDS base pointers (kills ~10 per-step ternary/cndmask selects).
//     Same byte addresses, same op order within the step, same math.
// Everything else byte-identical to R11 (329us): operand-swapped W.h^T,
// 3-product split GEMM (a0=Whi.hhi, a1=Whi.hlo, a2=Wlo.hhi, all C-init 0,
// xterm added AFTER), full 4-bit XOR swizzle, b64 packed writes,
// transposed xs, __expf/__fdividef tanh.

constexpr int BATCH   = 4096;
constexpr int SEQ     = 512;
constexpr int INP     = 2;
constexpr int HID     = 128;
constexpr int BM      = 16;    // batch rows per block
constexpr int THREADS = 512;   // 8 waves, 1 block/CU, 2 waves/SIMD
constexpr int XCHUNK  = 128;   // time steps of x staged per chunk

typedef short bf16x8 __attribute__((ext_vector_type(8)));
typedef float f32x4  __attribute__((ext_vector_type(4)));

__device__ inline unsigned short f2bf(float f) {          // round-to-nearest-even
    unsigned u = __float_as_uint(f);
    return (unsigned short)((u + 0x7FFFu + ((u >> 16) & 1u)) >> 16);
}
__device__ inline float bf2f(unsigned short s) {
    return __uint_as_float(((unsigned)s) << 16);
}
__device__ inline unsigned cvt_pk_bf16(float a, float b) { // lo=bf(a), hi=bf(b)
    unsigned r;
    asm("v_cvt_pk_bf16_f32 %0, %1, %2" : "=v"(r) : "v"(a), "v"(b));
    return r;
}

__global__ __launch_bounds__(THREADS, 2)
void elman_mfma10(const float* __restrict__ x,
                  const float* __restrict__ W_ih,
                  const float* __restrict__ b_ih,
                  const float* __restrict__ W_ho,
                  const float* __restrict__ b_ho,
                  float* __restrict__ out)
{
    __shared__ unsigned short hlds[2][2][BM][HID];  // [buf][hi/lo][r][j] = 16 KB
    __shared__ float2 xs[XCHUNK][BM];               // 16 KB, TRANSPOSED [t][b]
    __shared__ float red[BM][8];                    // epilogue partials

    const int tid  = threadIdx.x;
    const int lane = tid & 63;
    const int w    = tid >> 6;        // wave id 0..7 -> j-tile [16w, 16w+16)
    const int l15  = lane & 15;
    const int g    = lane >> 4;       // 0..3
    const int B0   = blockIdx.x * BM;

    // ---- stationary W fragments (A-operand), hi/lo bf16 split ----
    bf16x8 whi[4], wlo[4];
    {
        const float* Wrow = W_ih + (size_t)(w * 16 + l15) * (INP + HID) + INP;
        #pragma unroll
        for (int kt = 0; kt < 4; ++kt) {
            const int k0 = kt * 32 + g * 8;
            #pragma unroll
            for (int i = 0; i < 8; ++i) {
                const float wv = Wrow[k0 + i];
                const unsigned short hi = f2bf(wv);
                whi[kt][i] = (short)hi;
                wlo[kt][i] = (short)f2bf(wv - bf2f(hi));
            }
        }
    }

    // ---- per-reg coefficients for the 4 j's this lane RECEIVES in D ----
    float wx0v[4], wx1v[4], bjv[4], whov[4];
    #pragma unroll
    for (int reg = 0; reg < 4; ++reg) {
        const int jj = w * 16 + g * 4 + reg;
        const float* Wr = W_ih + (size_t)jj * (INP + HID);
        wx0v[reg] = Wr[0];
        wx1v[reg] = Wr[1];
        bjv[reg]  = b_ih[jj];
        whov[reg] = W_ho[jj];
    }

    // ---- hoisted swizzled LDS offsets (key = r<<4, full 4 bits) ----
    int roff[4];
    #pragma unroll
    for (int kt = 0; kt < 4; ++kt)
        roff[kt] = l15 * 256 + ((kt * 64 + g * 16) ^ (l15 << 4));
    const int woff = l15 * 256 + (((w * 32 + (g & 2) * 8)) ^ (l15 << 4)) + (g & 1) * 8;

    // ---- h0 = 0 ----
    reinterpret_cast<float4*>(hlds)[tid]       = float4{0.f, 0.f, 0.f, 0.f};
    reinterpret_cast<float4*>(hlds)[tid + 512] = float4{0.f, 0.f, 0.f, 0.f};

    // ---- stage x chunk 0, transposed: xs[t][b] ----
    const int sr = tid >> 5;            // 0..15 (batch row)
    const int so = (tid & 31) * 8;      // float offset within row's 256
    {
        const float* src = x + (size_t)(B0 + sr) * (SEQ * INP) + so;
        const float4 v0 = *reinterpret_cast<const float4*>(src);
        const float4 v1 = *reinterpret_cast<const float4*>(src + 4);
        const int t0 = so >> 1;
        xs[t0 + 0][sr] = float2{v0.x, v0.y};
        xs[t0 + 1][sr] = float2{v0.z, v0.w};
        xs[t0 + 2][sr] = float2{v1.x, v1.y};
        xs[t0 + 3][sr] = float2{v1.z, v1.w};
    }
    __syncthreads();

    char* hbA = (char*)&hlds[0][0][0][0];   // buf0 hi
    char* lbA = (char*)&hlds[0][1][0][0];   // buf0 lo
    char* hbB = (char*)&hlds[1][0][0][0];   // buf1 hi
    char* lbB = (char*)&hlds[1][1][0][0];   // buf1 lo

    float hv[4] = {0.f, 0.f, 0.f, 0.f};     // final-step h (row l15, 4 j's)

    // one step, EXACT v7 body: read (HP,LP), write (HN,LN), timestep TT
#define RNN_STEP(HP, LP, HN, LN, TT)                                           \
    {                                                                          \
        bf16x8 ahi[4], alo[4];                                                 \
        _Pragma("unroll")                                                      \
        for (int kt = 0; kt < 4; ++kt) {                                       \
            ahi[kt] = *reinterpret_cast<const bf16x8*>((HP) + roff[kt]);       \
            alo[kt] = *reinterpret_cast<const bf16x8*>((LP) + roff[kt]);       \
        }                                                                      \
        f32x4 a0 = {0.f, 0.f, 0.f, 0.f};                                       \
        f32x4 a1 = {0.f, 0.f, 0.f, 0.f};                                       \
        f32x4 a2 = {0.f, 0.f, 0.f, 0.f};                                       \
        _Pragma("unroll")                                                      \
        for (int kt = 0; kt < 4; ++kt) {                                       \
            a0 = __builtin_amdgcn_mfma_f32_16x16x32_bf16(whi[kt], ahi[kt], a0, 0, 0, 0); \
            a1 = __builtin_amdgcn_mfma_f32_16x16x32_bf16(whi[kt], alo[kt], a1, 0, 0, 0); \
            a2 = __builtin_amdgcn_mfma_f32_16x16x32_bf16(wlo[kt], ahi[kt], a2, 0, 0, 0); \
        }                                                                      \
        const float2 xv = xs[(TT)][l15];                                       \
        float hcur[4];                                                         \
        _Pragma("unroll")                                                      \
        for (int reg = 0; reg < 4; ++reg) {                                    \
            const float acc = (a0[reg] + a1[reg] + a2[reg])                    \
                            + fmaf(wx0v[reg], xv.x, fmaf(wx1v[reg], xv.y, bjv[reg])); \
            const float e = __expf(acc + acc);                                 \
            hcur[reg] = 1.0f - __fdividef(2.0f, e + 1.0f);   /* tanh(acc) */   \
            hv[reg]   = hcur[reg];                                             \
        }                                                                      \
        const unsigned c01 = cvt_pk_bf16(hcur[0], hcur[1]);                    \
        const unsigned c23 = cvt_pk_bf16(hcur[2], hcur[3]);                    \
        const float h0b = __uint_as_float(c01 << 16);                          \
        const float h1b = __uint_as_float(c01 & 0xFFFF0000u);                  \
        const float h2b = __uint_as_float(c23 << 16);                          \
        const float h3b = __uint_as_float(c23 & 0xFFFF0000u);                  \
        const unsigned l01 = cvt_pk_bf16(hcur[0] - h0b, hcur[1] - h1b);        \
        const unsigned l23 = cvt_pk_bf16(hcur[2] - h2b, hcur[3] - h3b);        \
        *reinterpret_cast<uint2*>((HN) + woff) = uint2{c01, c23};              \
        *reinterpret_cast<uint2*>((LN) + woff) = uint2{l01, l23};              \
        __syncthreads();                                                       \
    }

    #pragma unroll 1
    for (int t2 = 0; t2 < SEQ; t2 += 2) {
        const int tt = t2 & (XCHUNK - 1);
        if (t2 && tt == 0) {
            // previous end-of-step barrier guarantees xs no longer read
            const float* src = x + (size_t)(B0 + sr) * (SEQ * INP)
                                 + (size_t)(t2 >> 7) * (XCHUNK * INP) + so;
            const float4 v0 = *reinterpret_cast<const float4*>(src);
            const float4 v1 = *reinterpret_cast<const float4*>(src + 4);
            const int t0 = so >> 1;
            xs[t0 + 0][sr] = float2{v0.x, v0.y};
            xs[t0 + 1][sr] = float2{v0.z, v0.w};
            xs[t0 + 2][sr] = float2{v1.x, v1.y};
            xs[t0 + 3][sr] = float2{v1.z, v1.w};
            __syncthreads();
        }
        RNN_STEP(hbA, lbA, hbB, lbB, tt)       // even step: buf0 -> buf1
        RNN_STEP(hbB, lbB, hbA, lbA, tt + 1)   // odd step:  buf1 -> buf0
    }
#undef RNN_STEP

    // ---- epilogue: out[r] = sum_j Who[j]*h[r][j] + b_ho ----
    float part = 0.f;
    #pragma unroll
    for (int reg = 0; reg < 4; ++reg) part = fmaf(whov[reg], hv[reg], part);
    part += __shfl_xor(part, 16);   // sum over g bit0
    part += __shfl_xor(part, 32);   // sum over g bit1
    if (lane < 16) red[l15][w] = part;
    __syncthreads();
    if (tid < BM) {
        float s = b_ho[0];
        #pragma unroll
        for (int q = 0; q < 8; ++q) s += red[tid][q];
        out[B0 + tid] = s;
    }
}

extern "C" void kernel_launch(void* const* d_in, const int* in_sizes, int n_in,
                              void* d_out, int out_size, void* d_ws, size_t ws_size,
                              hipStream_t stream)
{
    (void)in_sizes; (void)n_in; (void)out_size; (void)d_ws; (void)ws_size;
    const float* x    = (const float*)d_in[0];
    const float* W_ih = (const float*)d_in[1];
    const float* b_ih = (const float*)d_in[2];
    const float* W_ho = (const float*)d_in[3];
    const float* b_ho = (const float*)d_in[4];
    float* out = (float*)d_out;

    dim3 grid(BATCH / BM);     // 256 blocks = 1 per CU
    dim3 block(THREADS);
    elman_mfma10<<<grid, block, 0, stream>>>(x, W_ih, b_ih, W_ho, b_ho, out);
}

// Round 16
// 302.505 us; speedup vs baseline: 2.1966x; 1.0333x over previous
//
#include <hip/hip_runtime.h>

// ElmanRNN via MFMA, v11 = v10 (312us) + x via register prefetch (no x LDS).
// BATCH=4096, SEQ=512, IN=2, HID=128, OUT=1
//
// Numeric constraints (R12-R14, empirically decisive):
//  - The EXACT per-element op sequence of the v7/v10 path is load-bearing
//    (edge-of-chaos recurrence; x-term preload into MFMA C-init -> 6e-2 fail).
//  - K-chain re-association is safe (R9), barrier type is safe, and moving
//    the SOURCE of xv (LDS vs global regs) is bit-identical by construction.
//
// v11 changes vs v10 (all zero-numeric-delta):
//  1. x read DIRECTLY from global into regs, depth-2 rolling prefetch folded
//     into the existing unroll-2 (issue t+2/t+3 loads at pair-top; ~1300cy
//     lead >> ~900cy HBM latency). Deletes: xs LDS (16 KB), per-step
//     ds_read_b64 x-read (-8 LDS instr/CU-step), chunk staging (whose writes
//     were 32-way bank-conflicted), staging barriers/branches.
//  2. step barrier = lgkmcnt(0)+s_barrier (no vmcnt drain) so prefetch loads
//     stay in flight across barriers. Legal: barrier only orders h LDS
//     traffic; x loads are lane-private registers.
// Everything else byte-identical to v10 (operand-swapped W.h^T 3-product
// split GEMM, full 4-bit XOR swizzle, b64 packed writes, unroll-2 ping-pong,
// __expf/__fdividef tanh).

constexpr int BATCH   = 4096;
constexpr int SEQ     = 512;
constexpr int INP     = 2;
constexpr int HID     = 128;
constexpr int BM      = 16;    // batch rows per block
constexpr int THREADS = 512;   // 8 waves, 1 block/CU, 2 waves/SIMD

typedef short bf16x8 __attribute__((ext_vector_type(8)));
typedef float f32x4  __attribute__((ext_vector_type(4)));

__device__ inline unsigned short f2bf(float f) {          // round-to-nearest-even
    unsigned u = __float_as_uint(f);
    return (unsigned short)((u + 0x7FFFu + ((u >> 16) & 1u)) >> 16);
}
__device__ inline float bf2f(unsigned short s) {
    return __uint_as_float(((unsigned)s) << 16);
}
__device__ inline unsigned cvt_pk_bf16(float a, float b) { // lo=bf(a), hi=bf(b)
    unsigned r;
    asm("v_cvt_pk_bf16_f32 %0, %1, %2" : "=v"(r) : "v"(a), "v"(b));
    return r;
}
// LDS-only barrier: drains ds ops, rendezvous; leaves VMEM (x prefetch)
// in flight. h ordering needs only lgkmcnt.
__device__ inline void lds_barrier() {
    asm volatile("s_waitcnt lgkmcnt(0)\n\ts_barrier" ::: "memory");
}

__global__ __launch_bounds__(THREADS, 2)
void elman_mfma11(const float* __restrict__ x,
                  const float* __restrict__ W_ih,
                  const float* __restrict__ b_ih,
                  const float* __restrict__ W_ho,
                  const float* __restrict__ b_ho,
                  float* __restrict__ out)
{
    __shared__ unsigned short hlds[2][2][BM][HID];  // [buf][hi/lo][r][j] = 16 KB
    __shared__ float red[BM][8];                    // epilogue partials

    const int tid  = threadIdx.x;
    const int lane = tid & 63;
    const int w    = tid >> 6;        // wave id 0..7 -> j-tile [16w, 16w+16)
    const int l15  = lane & 15;
    const int g    = lane >> 4;       // 0..3
    const int B0   = blockIdx.x * BM;

    // ---- stationary W fragments (A-operand), hi/lo bf16 split ----
    bf16x8 whi[4], wlo[4];
    {
        const float* Wrow = W_ih + (size_t)(w * 16 + l15) * (INP + HID) + INP;
        #pragma unroll
        for (int kt = 0; kt < 4; ++kt) {
            const int k0 = kt * 32 + g * 8;
            #pragma unroll
            for (int i = 0; i < 8; ++i) {
                const float wv = Wrow[k0 + i];
                const unsigned short hi = f2bf(wv);
                whi[kt][i] = (short)hi;
                wlo[kt][i] = (short)f2bf(wv - bf2f(hi));
            }
        }
    }

    // ---- per-reg coefficients for the 4 j's this lane RECEIVES in D ----
    float wx0v[4], wx1v[4], bjv[4], whov[4];
    #pragma unroll
    for (int reg = 0; reg < 4; ++reg) {
        const int jj = w * 16 + g * 4 + reg;
        const float* Wr = W_ih + (size_t)jj * (INP + HID);
        wx0v[reg] = Wr[0];
        wx1v[reg] = Wr[1];
        bjv[reg]  = b_ih[jj];
        whov[reg] = W_ho[jj];
    }

    // ---- hoisted swizzled LDS offsets (key = r<<4, full 4 bits) ----
    int roff[4];
    #pragma unroll
    for (int kt = 0; kt < 4; ++kt)
        roff[kt] = l15 * 256 + ((kt * 64 + g * 16) ^ (l15 << 4));
    const int woff = l15 * 256 + (((w * 32 + (g & 2) * 8)) ^ (l15 << 4)) + (g & 1) * 8;

    // ---- h0 = 0 ----
    reinterpret_cast<float4*>(hlds)[tid]       = float4{0.f, 0.f, 0.f, 0.f};
    reinterpret_cast<float4*>(hlds)[tid + 512] = float4{0.f, 0.f, 0.f, 0.f};

    // ---- per-lane x row; prime depth-2 prefetch (t=0, t=1) ----
    const float* xrow = x + (size_t)(B0 + l15) * (SEQ * INP);
    float2 xv0 = *reinterpret_cast<const float2*>(xrow);
    float2 xv1 = *reinterpret_cast<const float2*>(xrow + INP);

    __syncthreads();   // h0 visible

    char* hbA = (char*)&hlds[0][0][0][0];   // buf0 hi
    char* lbA = (char*)&hlds[0][1][0][0];   // buf0 lo
    char* hbB = (char*)&hlds[1][0][0][0];   // buf1 hi
    char* lbB = (char*)&hlds[1][1][0][0];   // buf1 lo

    float hv[4] = {0.f, 0.f, 0.f, 0.f};     // final-step h (row l15, 4 j's)

    // one step, EXACT v10 body (xv source moved to register XV — identical
    // values): read (HP,LP), write (HN,LN)
#define RNN_STEP(HP, LP, HN, LN, XV)                                           \
    {                                                                          \
        bf16x8 ahi[4], alo[4];                                                 \
        _Pragma("unroll")                                                      \
        for (int kt = 0; kt < 4; ++kt) {                                       \
            ahi[kt] = *reinterpret_cast<const bf16x8*>((HP) + roff[kt]);       \
            alo[kt] = *reinterpret_cast<const bf16x8*>((LP) + roff[kt]);       \
        }                                                                      \
        f32x4 a0 = {0.f, 0.f, 0.f, 0.f};                                       \
        f32x4 a1 = {0.f, 0.f, 0.f, 0.f};                                       \
        f32x4 a2 = {0.f, 0.f, 0.f, 0.f};                                       \
        _Pragma("unroll")                                                      \
        for (int kt = 0; kt < 4; ++kt) {                                       \
            a0 = __builtin_amdgcn_mfma_f32_16x16x32_bf16(whi[kt], ahi[kt], a0, 0, 0, 0); \
            a1 = __builtin_amdgcn_mfma_f32_16x16x32_bf16(whi[kt], alo[kt], a1, 0, 0, 0); \
            a2 = __builtin_amdgcn_mfma_f32_16x16x32_bf16(wlo[kt], ahi[kt], a2, 0, 0, 0); \
        }                                                                      \
        const float2 xv = (XV);                                                \
        float hcur[4];                                                         \
        _Pragma("unroll")                                                      \
        for (int reg = 0; reg < 4; ++reg) {                                    \
            const float acc = (a0[reg] + a1[reg] + a2[reg])                    \
                            + fmaf(wx0v[reg], xv.x, fmaf(wx1v[reg], xv.y, bjv[reg])); \
            const float e = __expf(acc + acc);                                 \
            hcur[reg] = 1.0f - __fdividef(2.0f, e + 1.0f);   /* tanh(acc) */   \
            hv[reg]   = hcur[reg];                                             \
        }                                                                      \
        const unsigned c01 = cvt_pk_bf16(hcur[0], hcur[1]);                    \
        const unsigned c23 = cvt_pk_bf16(hcur[2], hcur[3]);                    \
        const float h0b = __uint_as_float(c01 << 16);                          \
        const float h1b = __uint_as_float(c01 & 0xFFFF0000u);                  \
        const float h2b = __uint_as_float(c23 << 16);                          \
        const float h3b = __uint_as_float(c23 & 0xFFFF0000u);                  \
        const unsigned l01 = cvt_pk_bf16(hcur[0] - h0b, hcur[1] - h1b);        \
        const unsigned l23 = cvt_pk_bf16(hcur[2] - h2b, hcur[3] - h3b);        \
        *reinterpret_cast<uint2*>((HN) + woff) = uint2{c01, c23};              \
        *reinterpret_cast<uint2*>((LN) + woff) = uint2{l01, l23};              \
        lds_barrier();                                                         \
    }

    #pragma unroll 1
    for (int t2 = 0; t2 < SEQ; t2 += 2) {
        // depth-2 prefetch for steps t2+2, t2+3 (clamped on last iter; values
        // then unused). Issued before the two steps -> ~1300cy lead.
        const int tn = (t2 + 2 < SEQ) ? (t2 + 2) : 0;
        const float2 xn0 = *reinterpret_cast<const float2*>(xrow + (size_t)tn * INP);
        const float2 xn1 = *reinterpret_cast<const float2*>(xrow + (size_t)tn * INP + INP);

        RNN_STEP(hbA, lbA, hbB, lbB, xv0)       // even step: buf0 -> buf1
        RNN_STEP(hbB, lbB, hbA, lbA, xv1)       // odd step:  buf1 -> buf0

        xv0 = xn0;
        xv1 = xn1;
    }
#undef RNN_STEP

    // ---- epilogue: out[r] = sum_j Who[j]*h[r][j] + b_ho ----
    float part = 0.f;
    #pragma unroll
    for (int reg = 0; reg < 4; ++reg) part = fmaf(whov[reg], hv[reg], part);
    part += __shfl_xor(part, 16);   // sum over g bit0
    part += __shfl_xor(part, 32);   // sum over g bit1
    if (lane < 16) red[l15][w] = part;
    __syncthreads();
    if (tid < BM) {
        float s = b_ho[0];
        #pragma unroll
        for (int q = 0; q < 8; ++q) s += red[tid][q];
        out[B0 + tid] = s;
    }
}

extern "C" void kernel_launch(void* const* d_in, const int* in_sizes, int n_in,
                              void* d_out, int out_size, void* d_ws, size_t ws_size,
                              hipStream_t stream)
{
    (void)in_sizes; (void)n_in; (void)out_size; (void)d_ws; (void)ws_size;
    const float* x    = (const float*)d_in[0];
    const float* W_ih = (const float*)d_in[1];
    const float* b_ih = (const float*)d_in[2];
    const float* W_ho = (const float*)d_in[3];
    const float* b_ho = (const float*)d_in[4];
    float* out = (float*)d_out;

    dim3 grid(BATCH / BM);     // 256 blocks = 1 per CU
    dim3 block(THREADS);
    elman_mfma11<<<grid, block, 0, stream>>>(x, W_ih, b_ih, W_ho, b_ho, out);
}